// Round 10
// baseline (280.036 us; speedup 1.0000x reference)
//
#include <hip/hip_runtime.h>
#include <math.h>

#define NN 100000
#define NE 1600000
#define DD 64
#define NBUK 782          // ceil(NN/128), bucket = dst>>7
#define TILE 8192         // long runs (10.5 edges) -> low write amplification
#define NTB ((NE + TILE - 1) / TILE)   // 196 partition blocks
#define NWB 96            // weight-prep blocks
#define NPB ((NN + 255) / 256)         // 391 projection blocks
#define BSTRIDE 3072      // padded per-bucket capacity in tmp
#define SCAP 3072         // kscat2 LDS output staging capacity

typedef __attribute__((ext_vector_type(8))) _Float16 half8;
typedef __attribute__((ext_vector_type(4))) float f32x4;
typedef __attribute__((ext_vector_type(4))) _Float16 h4;
typedef __attribute__((ext_vector_type(2))) _Float16 f16x2;

__device__ __forceinline__ float gelu_exact(float v) {
    return 0.5f * v * (1.0f + erff(v * 0.7071067811865475f));
}

__device__ __forceinline__ f16x2 as_f16x2(unsigned int u) {
    union { unsigned int x; f16x2 h; } c; c.x = u; return c.h;
}
__device__ __forceinline__ unsigned short h_as_us(_Float16 h) {
    union { _Float16 h; unsigned short u; } c; c.h = h; return c.u;
}
__device__ __forceinline__ float us_as_f(unsigned short u) {
    union { unsigned short u; _Float16 h; } c; c.u = u; return (float)c.h;
}

// B-fragment read from a 64x64 fp16 chunk with 16B-unit XOR swizzle
#define BFRAG(W, row, u0) (*(const half8*)&W[(row)*64 + ((((u0) ^ ((row)&7)))<<3)])

// KFRONT: three independent jobs in ONE grid for co-residency latency hiding.
__global__ __launch_bounds__(256) void kfront(
    const int* __restrict__ ei, const float* __restrict__ rf,
    int* __restrict__ bcount, uint2* __restrict__ tmp,
    const float* __restrict__ Wp, const float* __restrict__ Wn,
    const float* __restrict__ w1, const float* __restrict__ w2,
    const float* __restrict__ cf,
    _Float16* __restrict__ whh, _Float16* __restrict__ wll,
    const float* __restrict__ x, const float* __restrict__ attw,
    float* __restrict__ es1, _Float16* __restrict__ xh)
{
    __shared__ int hist[NBUK];
    __shared__ int gbase[NBUK];
    int bid = blockIdx.x;
    int tid = threadIdx.x;

    if (bid < NTB) {
        // ---- partition tile ----
        for (int i = tid; i < NBUK; i += 256) hist[i] = 0;
        __syncthreads();
        int base = bid * TILE;
        int end  = min(base + TILE, NE);
        for (int e = base + tid; e < end; e += 256)
            atomicAdd(&hist[ei[NE + e] >> 7], 1);
        __syncthreads();
        for (int i = tid; i < NBUK; i += 256) {
            int c = hist[i];
            gbase[i] = c ? (i * BSTRIDE + atomicAdd(bcount + i, c)) : 0;
            hist[i] = 0;                  // reuse as ticket counter
        }
        __syncthreads();
        for (int e0 = base + tid; e0 < end; e0 += 256 * 4) {
            int srcs[4], dsts[4]; unsigned rfs[4];
            #pragma unroll
            for (int q = 0; q < 4; ++q) {
                int e = e0 + q * 256;
                if (e < end) {
                    srcs[q] = ei[e];
                    dsts[q] = ei[NE + e];
                    rfs[q]  = __float_as_uint(rf[e]);
                }
            }
            #pragma unroll
            for (int q = 0; q < 4; ++q) {
                int e = e0 + q * 256;
                if (e < end) {
                    int b = dsts[q] >> 7;
                    int t = atomicAdd(&hist[b], 1);
                    tmp[gbase[b] + t] = make_uint2(
                        (unsigned)srcs[q] | ((unsigned)(dsts[q] & 127) << 17),
                        rfs[q]);
                }
            }
        }
    } else if (bid < NTB + NWB) {
        // ---- weight prep: fp16 hi/lo split ----
        int t = (bid - NTB) * 256 + tid;   // 24576 total
        float alpha = 1.0f / (1.0f + __expf(-cf[0]));
        float beta  = 1.0f - alpha;
        float v;
        if (t < 8192) {
            int d = t >> 7, k = t & 127;
            v = (k < 64) ? alpha * Wp[d * 64 + k] : beta * Wn[d * 64 + (k - 64)];
        } else if (t < 16384) {
            v = w1[t - 8192];
        } else {
            v = w2[t - 16384];
        }
        _Float16 h = (_Float16)v;
        whh[t] = h;
        wll[t] = (_Float16)(v - (float)h);
    } else {
        // ---- attention projection + fp16 x ----
        int n = (bid - NTB - NWB) * 256 + tid;
        if (n >= NN) return;
        const float4* x4 = (const float4*)(x + (size_t)n * DD);
        float a = 0.f;
        #pragma unroll
        for (int i = 0; i < DD/4; ++i) {
            float4 v = x4[i];
            a += v.x*attw[4*i+0] + v.y*attw[4*i+1] + v.z*attw[4*i+2] + v.w*attw[4*i+3];
            h4 hv = {(_Float16)v.x, (_Float16)v.y, (_Float16)v.z, (_Float16)v.w};
            *(h4*)(xh + (size_t)n * DD + 4*i) = hv;
        }
        es1[n] = __expf(a);
    }
}

// KBS: single-block exclusive scan of 782 bucket counts -> bbase
__global__ __launch_bounds__(1024) void ks_bscan(
    const int* __restrict__ bcount, int* __restrict__ bbase)
{
    __shared__ int sa[1024], sb[1024];
    int t = threadIdx.x;
    int v = (t < NBUK) ? bcount[t] : 0;
    sa[t] = v;
    __syncthreads();
    int* s = sa; int* d = sb;
    #pragma unroll
    for (int o = 1; o < 1024; o <<= 1) {
        d[t] = s[t] + ((t >= o) ? s[t - o] : 0);
        __syncthreads();
        int* tmp = s; s = d; d = tmp;
    }
    if (t < NBUK) bbase[t] = s[t] - v;
    if (t == 0) bbase[NBUK] = NE;
}

// KSCAT2: block-per-bucket fine sort; gathers es1[src], packs fp16x2(es, es*rf);
// LDS-staged coalesced output.
__global__ __launch_bounds__(256) void kscat2(
    const uint2* __restrict__ tmp, const int* __restrict__ bcount,
    const int* __restrict__ bbase, const float* __restrict__ es1,
    int* __restrict__ off, uint2* __restrict__ sorted)
{
    __shared__ int hist[128], scn[128], tick[128];
    __shared__ uint2 obuf[SCAP];
    int b   = blockIdx.x;
    int tid = threadIdx.x;
    int si = b * BSTRIDE;        // input (padded tmp)
    int so = bbase[b];           // output (dense sorted)
    int m  = bcount[b];

    if (tid < 128) { hist[tid] = 0; tick[tid] = 0; }
    __syncthreads();

    for (int i = tid; i < m; i += 256)
        atomicAdd(&hist[tmp[si + i].x >> 17], 1);
    __syncthreads();

    if (tid < 128) scn[tid] = hist[tid];
    __syncthreads();
    #pragma unroll
    for (int o = 1; o < 128; o <<= 1) {
        int v = (tid < 128 && tid >= o) ? scn[tid - o] : 0;
        __syncthreads();
        if (tid < 128) scn[tid] += v;
        __syncthreads();
    }

    int nb0 = b * 128;
    if (tid < 128 && nb0 + tid < NN) off[nb0 + tid] = so + scn[tid] - hist[tid];
    if (b == NBUK - 1 && tid == 0) off[NN] = NE;
    __syncthreads();

    for (int i = tid; i < m; i += 256) {
        uint2 pr = tmp[si + i];
        int l   = pr.x >> 17;
        int src = pr.x & 0x1FFFF;
        float es = es1[src];
        float ef = es * __uint_as_float(pr.y);
        unsigned packed = (unsigned)h_as_us((_Float16)es)
                        | ((unsigned)h_as_us((_Float16)ef) << 16);
        int t = atomicAdd(&tick[l], 1);
        int lp = (scn[l] - hist[l]) + t;
        uint2 val = make_uint2((unsigned)src, packed);
        if (lp < SCAP) obuf[lp] = val;
        else sorted[so + lp] = val;      // statistically never (m <= ~2300)
    }
    __syncthreads();
    int mm = min(m, SCAP);
    for (int i = tid; i < mm; i += 256)
        sorted[so + i] = obuf[i];
}

// K4A v3: wave-per-node; wave-UNIFORM edge stream; fdot2 math; fp16 gathers.
// Output uv now fp16 (halves store + k4b5 load traffic; A-operand is fp16 anyway).
__global__ __launch_bounds__(256) void k4a_agg(
    const uint2* __restrict__ sorted, const int* __restrict__ off,
    const _Float16* __restrict__ xh, _Float16* __restrict__ uvh)
{
    int lane = threadIdx.x & 63;
    int n = blockIdx.x * 4 + (threadIdx.x >> 6);
    int r0 = __builtin_amdgcn_readfirstlane(off[n]);
    int r1 = __builtin_amdgcn_readfirstlane(off[n + 1]);
    const unsigned short* xs = (const unsigned short*)xh;

    float den = 0.f, u = 0.f, v = 0.f;
    const unsigned ONES = 0x3C003C00u;   // fp16x2 {1,1}
    int j = r0;
    for (; j + 8 <= r1; j += 8) {
        uint2 p[8];
        #pragma unroll
        for (int t = 0; t < 8; ++t) p[t] = sorted[j + t];
        unsigned xv[4];
        #pragma unroll
        for (int q = 0; q < 4; ++q) {
            unsigned a0 = xs[(size_t)p[2*q].x   * DD + lane];
            unsigned a1 = xs[(size_t)p[2*q+1].x * DD + lane];
            xv[q] = a0 | (a1 << 16);
        }
        #pragma unroll
        for (int q = 0; q < 4; ++q) {
            unsigned y0 = p[2*q].y, y1 = p[2*q+1].y;
            unsigned e2 = (y0 & 0xFFFFu) | (y1 << 16);
            unsigned f2 = (y0 >> 16) | (y1 & 0xFFFF0000u);
            v   = __builtin_amdgcn_fdot2(as_f16x2(xv[q]), as_f16x2(e2), v, false);
            u   = __builtin_amdgcn_fdot2(as_f16x2(xv[q]), as_f16x2(f2), u, false);
            den = __builtin_amdgcn_fdot2(as_f16x2(e2), as_f16x2(ONES), den, false);
        }
    }
    for (; j + 2 <= r1; j += 2) {
        uint2 p0 = sorted[j], p1 = sorted[j + 1];
        unsigned a0 = xs[(size_t)p0.x * DD + lane];
        unsigned a1 = xs[(size_t)p1.x * DD + lane];
        unsigned xv = a0 | (a1 << 16);
        unsigned e2 = (p0.y & 0xFFFFu) | (p1.y << 16);
        unsigned f2 = (p0.y >> 16) | (p1.y & 0xFFFF0000u);
        v   = __builtin_amdgcn_fdot2(as_f16x2(xv), as_f16x2(e2), v, false);
        u   = __builtin_amdgcn_fdot2(as_f16x2(xv), as_f16x2(f2), u, false);
        den = __builtin_amdgcn_fdot2(as_f16x2(e2), as_f16x2(ONES), den, false);
    }
    if (j < r1) {
        uint2 p0 = sorted[j];
        float xvf = us_as_f((unsigned short)xs[(size_t)p0.x * DD + lane]);
        float e = us_as_f((unsigned short)(p0.y & 0xFFFFu));
        float f = us_as_f((unsigned short)(p0.y >> 16));
        den += e; v += e * xvf; u += f * xvf;
    }
    float inv = (r1 > r0) ? 1.f / den : 0.f;
    uvh[(size_t)n * 128 + lane]      = (_Float16)(u * inv);
    uvh[(size_t)n * 128 + 64 + lane] = (_Float16)(v * inv);
}

// K4B5 v4: fp16 A-path. A-operands (uv, h, G) plain fp16 (no split8);
// weights fp16 hi/lo (2 MFMA per product, 96 total vs 144).
// All weight staging in 64x64 fp16 chunks (8KB each): LDS = 4*8K + 16K(Gt)
// = 49152 B -> 3 blocks/CU, 24 waves. 7 short barriers across 3 indep blocks.
__global__ __launch_bounds__(512, 6) void k4b5(
    const _Float16* __restrict__ uvh,
    const _Float16* __restrict__ whh, const _Float16* __restrict__ wll,
    const float* __restrict__ x,
    const float* __restrict__ g1, const float* __restrict__ be1,
    const float* __restrict__ bb1, const float* __restrict__ bb2,
    const float* __restrict__ g2, const float* __restrict__ be2,
    float* __restrict__ out)
{
    __shared__ _Float16 WAH[4096], WAL[4096];   // 64x64 chunk: Bmix k-half / w1 row-half
    __shared__ _Float16 W2H[4096], W2L[4096];   // w2 k-half
    __shared__ _Float16 Gt[8][1024];            // per-wave 16x64 (h, then G chunks)

    int tid  = threadIdx.x;
    int lane = tid & 63;
    int wv   = tid >> 6;
    int quad = lane >> 4, l16 = lane & 15;
    int nb = blockIdx.x * 128 + wv * 16;
    _Float16* gt = Gt[wv];

    // ---- upfront global loads ----
    const _Float16* arow = uvh + (size_t)min(nb + l16, NN - 1) * 128;
    half8 av[4];
    #pragma unroll
    for (int ks = 0; ks < 4; ++ks)
        av[ks] = *(const half8*)(arow + ks*32 + quad*8);
    float xr[4][4];
    #pragma unroll
    for (int r = 0; r < 4; ++r) {
        size_t nld = (size_t)min(nb + quad*4 + r, NN - 1) * 64;
        #pragma unroll
        for (int nt = 0; nt < 4; ++nt) xr[r][nt] = x[nld + nt*16 + l16];
    }

    // staging coords: 512 threads x one 16B unit each
    int srow = tid >> 3, su = tid & 7;
    int sdst = srow*64 + ((su ^ (srow & 7)) << 3);

    // ---- stage Bmix k0-63 + w2 k0-63 ----
    *(half8*)&WAH[sdst] = *(const half8*)&whh[srow*128 + su*8];
    *(half8*)&WAL[sdst] = *(const half8*)&wll[srow*128 + su*8];
    *(half8*)&W2H[sdst] = *(const half8*)&whh[16384 + srow*128 + su*8];
    *(half8*)&W2L[sdst] = *(const half8*)&wll[16384 + srow*128 + su*8];
    __syncthreads();                                            // B1

    // ---- GEMM0a: k 0..63 ----
    f32x4 acc0[4] = {};
    #pragma unroll
    for (int ks = 0; ks < 2; ++ks) {
        int u0 = ks*4 + quad;
        #pragma unroll
        for (int nt = 0; nt < 4; ++nt) {
            int row = nt*16 + l16;
            acc0[nt] = __builtin_amdgcn_mfma_f32_16x16x32_f16(av[ks], BFRAG(WAH,row,u0), acc0[nt], 0,0,0);
            acc0[nt] = __builtin_amdgcn_mfma_f32_16x16x32_f16(av[ks], BFRAG(WAL,row,u0), acc0[nt], 0,0,0);
        }
    }
    __syncthreads();                                            // B2
    *(half8*)&WAH[sdst] = *(const half8*)&whh[srow*128 + 64 + su*8];
    *(half8*)&WAL[sdst] = *(const half8*)&wll[srow*128 + 64 + su*8];
    __syncthreads();                                            // B3

    // ---- GEMM0b: k 64..127 ----
    #pragma unroll
    for (int ks = 0; ks < 2; ++ks) {
        int u0 = ks*4 + quad;
        #pragma unroll
        for (int nt = 0; nt < 4; ++nt) {
            int row = nt*16 + l16;
            acc0[nt] = __builtin_amdgcn_mfma_f32_16x16x32_f16(av[2+ks], BFRAG(WAH,row,u0), acc0[nt], 0,0,0);
            acc0[nt] = __builtin_amdgcn_mfma_f32_16x16x32_f16(av[2+ks], BFRAG(WAL,row,u0), acc0[nt], 0,0,0);
        }
    }

    // ---- gelu + residual + LN1 -> hn f32 regs + fp16 h tile ----
    float hn[4][4];
    #pragma unroll
    for (int r = 0; r < 4; ++r) {
        float hv[4];
        #pragma unroll
        for (int nt = 0; nt < 4; ++nt)
            hv[nt] = gelu_exact(acc0[nt][r]) + xr[r][nt];
        float s = hv[0] + hv[1] + hv[2] + hv[3];
        #pragma unroll
        for (int o = 1; o < 16; o <<= 1) s += __shfl_xor(s, o);
        float mu = s * (1.0f/64.0f);
        float q = 0.f;
        #pragma unroll
        for (int nt = 0; nt < 4; ++nt) { float t = hv[nt] - mu; q += t*t; }
        #pragma unroll
        for (int o = 1; o < 16; o <<= 1) q += __shfl_xor(q, o);
        float rs = rsqrtf(q * (1.0f/64.0f) + 1e-5f);
        int row = quad*4 + r;
        #pragma unroll
        for (int nt = 0; nt < 4; ++nt) {
            int c = nt*16 + l16;
            float h = (hv[nt] - mu) * rs * g1[c] + be1[c];
            hn[r][nt] = h;
            int u = c >> 3;
            gt[row*64 + ((u ^ (row & 7)) << 3) + (c & 7)] = (_Float16)h;
        }
    }
    // A1 fragments from per-wave h tile (no cross-wave sync needed)
    half8 ah1[2];
    #pragma unroll
    for (int ks = 0; ks < 2; ++ks) {
        int u0 = ks*4 + quad;
        ah1[ks] = *(const half8*)&gt[l16*64 + ((u0 ^ (l16 & 7)) << 3)];
    }
    __syncthreads();                                            // B4
    *(half8*)&WAH[sdst] = *(const half8*)&whh[8192 + srow*64 + su*8];
    *(half8*)&WAL[sdst] = *(const half8*)&wll[8192 + srow*64 + su*8];
    __syncthreads();                                            // B5

    f32x4 acc2[4] = {};
    // ================ half 0: G cols 0..63 ================
    {
        f32x4 a1[4] = {};
        #pragma unroll
        for (int ks = 0; ks < 2; ++ks) {
            int u0 = ks*4 + quad;
            #pragma unroll
            for (int t = 0; t < 4; ++t) {
                int row = t*16 + l16;
                a1[t] = __builtin_amdgcn_mfma_f32_16x16x32_f16(ah1[ks], BFRAG(WAH,row,u0), a1[t], 0,0,0);
                a1[t] = __builtin_amdgcn_mfma_f32_16x16x32_f16(ah1[ks], BFRAG(WAL,row,u0), a1[t], 0,0,0);
            }
        }
        #pragma unroll
        for (int t = 0; t < 4; ++t) {
            float b1v = bb1[t*16 + l16];
            #pragma unroll
            for (int r = 0; r < 4; ++r) {
                int row = quad*4 + r;
                int c = t*16 + l16;
                int u = c >> 3;
                gt[row*64 + ((u ^ (row & 7)) << 3) + (c & 7)] =
                    (_Float16)gelu_exact(a1[t][r] + b1v);
            }
        }
        #pragma unroll
        for (int ks2 = 0; ks2 < 2; ++ks2) {
            int u0 = ks2*4 + quad;
            half8 ag = *(const half8*)&gt[l16*64 + ((u0 ^ (l16 & 7)) << 3)];
            #pragma unroll
            for (int nt2 = 0; nt2 < 4; ++nt2) {
                int row = nt2*16 + l16;
                acc2[nt2] = __builtin_amdgcn_mfma_f32_16x16x32_f16(ag, BFRAG(W2H,row,u0), acc2[nt2], 0,0,0);
                acc2[nt2] = __builtin_amdgcn_mfma_f32_16x16x32_f16(ag, BFRAG(W2L,row,u0), acc2[nt2], 0,0,0);
            }
        }
    }
    __syncthreads();                                            // B6
    *(half8*)&WAH[sdst] = *(const half8*)&whh[8192 + (64 + srow)*64 + su*8];
    *(half8*)&WAL[sdst] = *(const half8*)&wll[8192 + (64 + srow)*64 + su*8];
    *(half8*)&W2H[sdst] = *(const half8*)&whh[16384 + srow*128 + 64 + su*8];
    *(half8*)&W2L[sdst] = *(const half8*)&wll[16384 + srow*128 + 64 + su*8];
    __syncthreads();                                            // B7
    // ================ half 1: G cols 64..127 ================
    {
        f32x4 a1[4] = {};
        #pragma unroll
        for (int ks = 0; ks < 2; ++ks) {
            int u0 = ks*4 + quad;
            #pragma unroll
            for (int t = 0; t < 4; ++t) {
                int row = t*16 + l16;
                a1[t] = __builtin_amdgcn_mfma_f32_16x16x32_f16(ah1[ks], BFRAG(WAH,row,u0), a1[t], 0,0,0);
                a1[t] = __builtin_amdgcn_mfma_f32_16x16x32_f16(ah1[ks], BFRAG(WAL,row,u0), a1[t], 0,0,0);
            }
        }
        #pragma unroll
        for (int t = 0; t < 4; ++t) {
            float b1v = bb1[64 + t*16 + l16];
            #pragma unroll
            for (int r = 0; r < 4; ++r) {
                int row = quad*4 + r;
                int c = t*16 + l16;
                int u = c >> 3;
                gt[row*64 + ((u ^ (row & 7)) << 3) + (c & 7)] =
                    (_Float16)gelu_exact(a1[t][r] + b1v);
            }
        }
        #pragma unroll
        for (int ks2 = 0; ks2 < 2; ++ks2) {
            int u0 = ks2*4 + quad;
            half8 ag = *(const half8*)&gt[l16*64 + ((u0 ^ (l16 & 7)) << 3)];
            #pragma unroll
            for (int nt2 = 0; nt2 < 4; ++nt2) {
                int row = nt2*16 + l16;
                acc2[nt2] = __builtin_amdgcn_mfma_f32_16x16x32_f16(ag, BFRAG(W2H,row,u0), acc2[nt2], 0,0,0);
                acc2[nt2] = __builtin_amdgcn_mfma_f32_16x16x32_f16(ag, BFRAG(W2L,row,u0), acc2[nt2], 0,0,0);
            }
        }
    }

    // ---- epilogue: m = acc2 + hn + b2; out = LN2(m) ----
    #pragma unroll
    for (int r = 0; r < 4; ++r) {
        int n = nb + quad * 4 + r;
        float mv[4];
        #pragma unroll
        for (int nt = 0; nt < 4; ++nt)
            mv[nt] = acc2[nt][r] + hn[r][nt] + bb2[nt*16 + l16];
        float s = mv[0] + mv[1] + mv[2] + mv[3];
        #pragma unroll
        for (int o = 1; o < 16; o <<= 1) s += __shfl_xor(s, o);
        float mu = s * (1.0f/64.0f);
        float q = 0.f;
        #pragma unroll
        for (int nt = 0; nt < 4; ++nt) { float t = mv[nt] - mu; q += t*t; }
        #pragma unroll
        for (int o = 1; o < 16; o <<= 1) q += __shfl_xor(q, o);
        float rs = rsqrtf(q * (1.0f/64.0f) + 1e-5f);
        if (n < NN) {
            #pragma unroll
            for (int nt = 0; nt < 4; ++nt) {
                int c = nt*16 + l16;
                out[(size_t)n * 64 + c] = (mv[nt] - mu) * rs * g2[c] + be2[c];
            }
        }
    }
}

extern "C" void kernel_launch(void* const* d_in, const int* in_sizes, int n_in,
                              void* d_out, int out_size, void* d_ws, size_t ws_size,
                              hipStream_t stream) {
    const float* x    = (const float*)d_in[0];
    const int*   ei   = (const int*)d_in[1];
    const float* rf   = (const float*)d_in[2];
    const float* Wp   = (const float*)d_in[3];
    const float* Wn   = (const float*)d_in[4];
    const float* attw = (const float*)d_in[5];
    const float* cf   = (const float*)d_in[6];
    const float* w1   = (const float*)d_in[7];
    const float* b1   = (const float*)d_in[8];
    const float* w2   = (const float*)d_in[9];
    const float* b2   = (const float*)d_in[10];
    const float* g1   = (const float*)d_in[11];
    const float* be1  = (const float*)d_in[12];
    const float* g2   = (const float*)d_in[13];
    const float* be2  = (const float*)d_in[14];
    float* out = (float*)d_out;

    float* ws = (float*)d_ws;
    float*     es1 = ws;                                   // NN f32
    _Float16*  uvh = (_Float16*)(es1 + NN);                // NN*128 fp16
    _Float16*  whh = uvh + (size_t)NN * 128;               // 24576 fp16
    _Float16*  wll = whh + 24576;                          // 24576 fp16
    uint2*  sorted = (uint2*)(wll + 24576);                // NE uint2
    int*    off    = (int*)(sorted + NE);                  // NN+1
    int*    bcount = off + NN + 1;                         // NBUK
    int*    bbase  = bcount + NBUK;                        // NBUK+1
    uintptr_t xp = ((uintptr_t)(bbase + NBUK + 1) + 15) & ~(uintptr_t)15;
    _Float16* xh = (_Float16*)xp;                          // NN*64 fp16
    uint2*  tmp    = (uint2*)uvh;                          // padded NBUK*BSTRIDE uint2 (19.2MB < 25.6MB)

    hipMemsetAsync(bcount, 0, NBUK * sizeof(int), stream);

    kfront    <<<NTB + NWB + NPB, 256, 0, stream>>>(ei, rf, bcount, tmp,
                 Wp, Wn, w1, w2, cf, whh, wll, x, attw, es1, xh);
    ks_bscan  <<<1, 1024, 0, stream>>>(bcount, bbase);
    kscat2    <<<NBUK, 256, 0, stream>>>(tmp, bcount, bbase, es1, off, sorted);
    k4a_agg   <<<NN/4, 256, 0, stream>>>(sorted, off, xh, uvh);
    k4b5      <<<(NN+127)/128, 512, 0, stream>>>(uvh, whh, wll, x, g1, be1, b1, b2, g2, be2, out);
}

// Round 11
// 255.351 us; speedup vs baseline: 1.0967x; 1.0967x over previous
//
#include <hip/hip_runtime.h>
#include <math.h>

#define NN 100000
#define NE 1600000
#define DD 64
#define NBUK 782          // ceil(NN/128), bucket = dst>>7
#define TILE 8192         // long runs (10.5 edges) -> low write amplification
#define NTB ((NE + TILE - 1) / TILE)   // 196 partition blocks
#define NWB 96            // weight-prep blocks
#define NPB ((NN + 255) / 256)         // 391 projection blocks
#define BSTRIDE 3072      // padded per-bucket capacity in tmp
#define SCAP 3072         // kscat2 LDS output staging capacity

typedef __attribute__((ext_vector_type(8))) _Float16 half8;
typedef __attribute__((ext_vector_type(4))) float f32x4;
typedef __attribute__((ext_vector_type(4))) _Float16 h4;
typedef __attribute__((ext_vector_type(2))) _Float16 f16x2;

__device__ __forceinline__ float gelu_exact(float v) {
    return 0.5f * v * (1.0f + erff(v * 0.7071067811865475f));
}

__device__ __forceinline__ f16x2 as_f16x2(unsigned int u) {
    union { unsigned int x; f16x2 h; } c; c.x = u; return c.h;
}
__device__ __forceinline__ unsigned short h_as_us(_Float16 h) {
    union { _Float16 h; unsigned short u; } c; c.h = h; return c.u;
}
__device__ __forceinline__ float us_as_f(unsigned short u) {
    union { unsigned short u; _Float16 h; } c; c.u = u; return (float)c.h;
}

// B-fragment read from a 64x64 fp16 chunk with 16B-unit XOR swizzle
#define BFRAG(W, row, u0) (*(const half8*)&W[(row)*64 + ((((u0) ^ ((row)&7)))<<3)])

// KFRONT: three independent jobs in ONE grid for co-residency latency hiding.
__global__ __launch_bounds__(256) void kfront(
    const int* __restrict__ ei, const float* __restrict__ rf,
    int* __restrict__ bcount, uint2* __restrict__ tmp,
    const float* __restrict__ Wp, const float* __restrict__ Wn,
    const float* __restrict__ w1, const float* __restrict__ w2,
    const float* __restrict__ cf,
    _Float16* __restrict__ whh, _Float16* __restrict__ wll,
    const float* __restrict__ x, const float* __restrict__ attw,
    float* __restrict__ es1, _Float16* __restrict__ xh)
{
    __shared__ int hist[NBUK];
    __shared__ int gbase[NBUK];
    int bid = blockIdx.x;
    int tid = threadIdx.x;

    if (bid < NTB) {
        // ---- partition tile ----
        for (int i = tid; i < NBUK; i += 256) hist[i] = 0;
        __syncthreads();
        int base = bid * TILE;
        int end  = min(base + TILE, NE);
        for (int e = base + tid; e < end; e += 256)
            atomicAdd(&hist[ei[NE + e] >> 7], 1);
        __syncthreads();
        for (int i = tid; i < NBUK; i += 256) {
            int c = hist[i];
            gbase[i] = c ? (i * BSTRIDE + atomicAdd(bcount + i, c)) : 0;
            hist[i] = 0;                  // reuse as ticket counter
        }
        __syncthreads();
        for (int e0 = base + tid; e0 < end; e0 += 256 * 4) {
            int srcs[4], dsts[4]; unsigned rfs[4];
            #pragma unroll
            for (int q = 0; q < 4; ++q) {
                int e = e0 + q * 256;
                if (e < end) {
                    srcs[q] = ei[e];
                    dsts[q] = ei[NE + e];
                    rfs[q]  = __float_as_uint(rf[e]);
                }
            }
            #pragma unroll
            for (int q = 0; q < 4; ++q) {
                int e = e0 + q * 256;
                if (e < end) {
                    int b = dsts[q] >> 7;
                    int t = atomicAdd(&hist[b], 1);
                    tmp[gbase[b] + t] = make_uint2(
                        (unsigned)srcs[q] | ((unsigned)(dsts[q] & 127) << 17),
                        rfs[q]);
                }
            }
        }
    } else if (bid < NTB + NWB) {
        // ---- weight prep: fp16 hi/lo split ----
        int t = (bid - NTB) * 256 + tid;   // 24576 total
        float alpha = 1.0f / (1.0f + __expf(-cf[0]));
        float beta  = 1.0f - alpha;
        float v;
        if (t < 8192) {
            int d = t >> 7, k = t & 127;
            v = (k < 64) ? alpha * Wp[d * 64 + k] : beta * Wn[d * 64 + (k - 64)];
        } else if (t < 16384) {
            v = w1[t - 8192];
        } else {
            v = w2[t - 16384];
        }
        _Float16 h = (_Float16)v;
        whh[t] = h;
        wll[t] = (_Float16)(v - (float)h);
    } else {
        // ---- attention projection + fp16 x ----
        int n = (bid - NTB - NWB) * 256 + tid;
        if (n >= NN) return;
        const float4* x4 = (const float4*)(x + (size_t)n * DD);
        float a = 0.f;
        #pragma unroll
        for (int i = 0; i < DD/4; ++i) {
            float4 v = x4[i];
            a += v.x*attw[4*i+0] + v.y*attw[4*i+1] + v.z*attw[4*i+2] + v.w*attw[4*i+3];
            h4 hv = {(_Float16)v.x, (_Float16)v.y, (_Float16)v.z, (_Float16)v.w};
            *(h4*)(xh + (size_t)n * DD + 4*i) = hv;
        }
        es1[n] = __expf(a);
    }
}

// KBS: single-block exclusive scan of 782 bucket counts -> bbase
__global__ __launch_bounds__(1024) void ks_bscan(
    const int* __restrict__ bcount, int* __restrict__ bbase)
{
    __shared__ int sa[1024], sb[1024];
    int t = threadIdx.x;
    int v = (t < NBUK) ? bcount[t] : 0;
    sa[t] = v;
    __syncthreads();
    int* s = sa; int* d = sb;
    #pragma unroll
    for (int o = 1; o < 1024; o <<= 1) {
        d[t] = s[t] + ((t >= o) ? s[t - o] : 0);
        __syncthreads();
        int* tmp = s; s = d; d = tmp;
    }
    if (t < NBUK) bbase[t] = s[t] - v;
    if (t == 0) bbase[NBUK] = NE;
}

// KSCAT2: block-per-bucket fine sort; gathers es1[src], packs fp16x2(es, es*rf);
// LDS-staged coalesced output.
__global__ __launch_bounds__(256) void kscat2(
    const uint2* __restrict__ tmp, const int* __restrict__ bcount,
    const int* __restrict__ bbase, const float* __restrict__ es1,
    int* __restrict__ off, uint2* __restrict__ sorted)
{
    __shared__ int hist[128], scn[128], tick[128];
    __shared__ uint2 obuf[SCAP];
    int b   = blockIdx.x;
    int tid = threadIdx.x;
    int si = b * BSTRIDE;        // input (padded tmp)
    int so = bbase[b];           // output (dense sorted)
    int m  = bcount[b];

    if (tid < 128) { hist[tid] = 0; tick[tid] = 0; }
    __syncthreads();

    for (int i = tid; i < m; i += 256)
        atomicAdd(&hist[tmp[si + i].x >> 17], 1);
    __syncthreads();

    if (tid < 128) scn[tid] = hist[tid];
    __syncthreads();
    #pragma unroll
    for (int o = 1; o < 128; o <<= 1) {
        int v = (tid < 128 && tid >= o) ? scn[tid - o] : 0;
        __syncthreads();
        if (tid < 128) scn[tid] += v;
        __syncthreads();
    }

    int nb0 = b * 128;
    if (tid < 128 && nb0 + tid < NN) off[nb0 + tid] = so + scn[tid] - hist[tid];
    if (b == NBUK - 1 && tid == 0) off[NN] = NE;
    __syncthreads();

    for (int i = tid; i < m; i += 256) {
        uint2 pr = tmp[si + i];
        int l   = pr.x >> 17;
        int src = pr.x & 0x1FFFF;
        float es = es1[src];
        float ef = es * __uint_as_float(pr.y);
        unsigned packed = (unsigned)h_as_us((_Float16)es)
                        | ((unsigned)h_as_us((_Float16)ef) << 16);
        int t = atomicAdd(&tick[l], 1);
        int lp = (scn[l] - hist[l]) + t;
        uint2 val = make_uint2((unsigned)src, packed);
        if (lp < SCAP) obuf[lp] = val;
        else sorted[so + lp] = val;      // statistically never (m <= ~2300)
    }
    __syncthreads();
    int mm = min(m, SCAP);
    for (int i = tid; i < mm; i += 256)
        sorted[so + i] = obuf[i];
}

// K4A v3: wave-per-node; wave-UNIFORM edge stream; fdot2 math; fp16 gathers.
__global__ __launch_bounds__(256) void k4a_agg(
    const uint2* __restrict__ sorted, const int* __restrict__ off,
    const _Float16* __restrict__ xh, _Float16* __restrict__ uvh)
{
    int lane = threadIdx.x & 63;
    int n = blockIdx.x * 4 + (threadIdx.x >> 6);
    int r0 = __builtin_amdgcn_readfirstlane(off[n]);
    int r1 = __builtin_amdgcn_readfirstlane(off[n + 1]);
    const unsigned short* xs = (const unsigned short*)xh;

    float den = 0.f, u = 0.f, v = 0.f;
    const unsigned ONES = 0x3C003C00u;   // fp16x2 {1,1}
    int j = r0;
    for (; j + 8 <= r1; j += 8) {
        uint2 p[8];
        #pragma unroll
        for (int t = 0; t < 8; ++t) p[t] = sorted[j + t];
        unsigned xv[4];
        #pragma unroll
        for (int q = 0; q < 4; ++q) {
            unsigned a0 = xs[(size_t)p[2*q].x   * DD + lane];
            unsigned a1 = xs[(size_t)p[2*q+1].x * DD + lane];
            xv[q] = a0 | (a1 << 16);
        }
        #pragma unroll
        for (int q = 0; q < 4; ++q) {
            unsigned y0 = p[2*q].y, y1 = p[2*q+1].y;
            unsigned e2 = (y0 & 0xFFFFu) | (y1 << 16);
            unsigned f2 = (y0 >> 16) | (y1 & 0xFFFF0000u);
            v   = __builtin_amdgcn_fdot2(as_f16x2(xv[q]), as_f16x2(e2), v, false);
            u   = __builtin_amdgcn_fdot2(as_f16x2(xv[q]), as_f16x2(f2), u, false);
            den = __builtin_amdgcn_fdot2(as_f16x2(e2), as_f16x2(ONES), den, false);
        }
    }
    for (; j + 2 <= r1; j += 2) {
        uint2 p0 = sorted[j], p1 = sorted[j + 1];
        unsigned a0 = xs[(size_t)p0.x * DD + lane];
        unsigned a1 = xs[(size_t)p1.x * DD + lane];
        unsigned xv = a0 | (a1 << 16);
        unsigned e2 = (p0.y & 0xFFFFu) | (p1.y << 16);
        unsigned f2 = (p0.y >> 16) | (p1.y & 0xFFFF0000u);
        v   = __builtin_amdgcn_fdot2(as_f16x2(xv), as_f16x2(e2), v, false);
        u   = __builtin_amdgcn_fdot2(as_f16x2(xv), as_f16x2(f2), u, false);
        den = __builtin_amdgcn_fdot2(as_f16x2(e2), as_f16x2(ONES), den, false);
    }
    if (j < r1) {
        uint2 p0 = sorted[j];
        float xvf = us_as_f((unsigned short)xs[(size_t)p0.x * DD + lane]);
        float e = us_as_f((unsigned short)(p0.y & 0xFFFFu));
        float f = us_as_f((unsigned short)(p0.y >> 16));
        den += e; v += e * xvf; u += f * xvf;
    }
    float inv = (r1 > r0) ? 1.f / den : 0.f;
    uvh[(size_t)n * 128 + lane]      = (_Float16)(u * inv);
    uvh[(size_t)n * 128 + 64 + lane] = (_Float16)(v * inv);
}

// K4B5 v4b: fp16 A-path (96 MFMA, no split8), 49152 B LDS.
// launch_bounds (512,4): r10's (512,6) forced VGPR=40 -> scratch spills
// (WRITE_SIZE 100MB). 128-VGPR cap removes spills; LDS allows 3 blocks/CU
// if the allocator lands <=85 VGPR, else 2 (r9 parity with less work).
__global__ __launch_bounds__(512, 4) void k4b5(
    const _Float16* __restrict__ uvh,
    const _Float16* __restrict__ whh, const _Float16* __restrict__ wll,
    const float* __restrict__ x,
    const float* __restrict__ g1, const float* __restrict__ be1,
    const float* __restrict__ bb1, const float* __restrict__ bb2,
    const float* __restrict__ g2, const float* __restrict__ be2,
    float* __restrict__ out)
{
    __shared__ _Float16 WAH[4096], WAL[4096];   // 64x64 chunk: Bmix k-half / w1 row-half
    __shared__ _Float16 W2H[4096], W2L[4096];   // w2 k-half
    __shared__ _Float16 Gt[8][1024];            // per-wave 16x64 (h, then G chunks)

    int tid  = threadIdx.x;
    int lane = tid & 63;
    int wv   = tid >> 6;
    int quad = lane >> 4, l16 = lane & 15;
    int nb = blockIdx.x * 128 + wv * 16;
    _Float16* gt = Gt[wv];

    // ---- upfront global loads ----
    const _Float16* arow = uvh + (size_t)min(nb + l16, NN - 1) * 128;
    half8 av[4];
    #pragma unroll
    for (int ks = 0; ks < 4; ++ks)
        av[ks] = *(const half8*)(arow + ks*32 + quad*8);
    float xr[4][4];
    #pragma unroll
    for (int r = 0; r < 4; ++r) {
        size_t nld = (size_t)min(nb + quad*4 + r, NN - 1) * 64;
        #pragma unroll
        for (int nt = 0; nt < 4; ++nt) xr[r][nt] = x[nld + nt*16 + l16];
    }

    // staging coords: 512 threads x one 16B unit each
    int srow = tid >> 3, su = tid & 7;
    int sdst = srow*64 + ((su ^ (srow & 7)) << 3);

    // ---- stage Bmix k0-63 + w2 k0-63 ----
    *(half8*)&WAH[sdst] = *(const half8*)&whh[srow*128 + su*8];
    *(half8*)&WAL[sdst] = *(const half8*)&wll[srow*128 + su*8];
    *(half8*)&W2H[sdst] = *(const half8*)&whh[16384 + srow*128 + su*8];
    *(half8*)&W2L[sdst] = *(const half8*)&wll[16384 + srow*128 + su*8];
    __syncthreads();                                            // B1

    // ---- GEMM0a: k 0..63 ----
    f32x4 acc0[4] = {};
    #pragma unroll
    for (int ks = 0; ks < 2; ++ks) {
        int u0 = ks*4 + quad;
        #pragma unroll
        for (int nt = 0; nt < 4; ++nt) {
            int row = nt*16 + l16;
            acc0[nt] = __builtin_amdgcn_mfma_f32_16x16x32_f16(av[ks], BFRAG(WAH,row,u0), acc0[nt], 0,0,0);
            acc0[nt] = __builtin_amdgcn_mfma_f32_16x16x32_f16(av[ks], BFRAG(WAL,row,u0), acc0[nt], 0,0,0);
        }
    }
    __syncthreads();                                            // B2
    *(half8*)&WAH[sdst] = *(const half8*)&whh[srow*128 + 64 + su*8];
    *(half8*)&WAL[sdst] = *(const half8*)&wll[srow*128 + 64 + su*8];
    __syncthreads();                                            // B3

    // ---- GEMM0b: k 64..127 ----
    #pragma unroll
    for (int ks = 0; ks < 2; ++ks) {
        int u0 = ks*4 + quad;
        #pragma unroll
        for (int nt = 0; nt < 4; ++nt) {
            int row = nt*16 + l16;
            acc0[nt] = __builtin_amdgcn_mfma_f32_16x16x32_f16(av[2+ks], BFRAG(WAH,row,u0), acc0[nt], 0,0,0);
            acc0[nt] = __builtin_amdgcn_mfma_f32_16x16x32_f16(av[2+ks], BFRAG(WAL,row,u0), acc0[nt], 0,0,0);
        }
    }

    // ---- gelu + residual + LN1 -> hn f32 regs + fp16 h tile ----
    float hn[4][4];
    #pragma unroll
    for (int r = 0; r < 4; ++r) {
        float hv[4];
        #pragma unroll
        for (int nt = 0; nt < 4; ++nt)
            hv[nt] = gelu_exact(acc0[nt][r]) + xr[r][nt];
        float s = hv[0] + hv[1] + hv[2] + hv[3];
        #pragma unroll
        for (int o = 1; o < 16; o <<= 1) s += __shfl_xor(s, o);
        float mu = s * (1.0f/64.0f);
        float q = 0.f;
        #pragma unroll
        for (int nt = 0; nt < 4; ++nt) { float t = hv[nt] - mu; q += t*t; }
        #pragma unroll
        for (int o = 1; o < 16; o <<= 1) q += __shfl_xor(q, o);
        float rs = rsqrtf(q * (1.0f/64.0f) + 1e-5f);
        int row = quad*4 + r;
        #pragma unroll
        for (int nt = 0; nt < 4; ++nt) {
            int c = nt*16 + l16;
            float h = (hv[nt] - mu) * rs * g1[c] + be1[c];
            hn[r][nt] = h;
            int u = c >> 3;
            gt[row*64 + ((u ^ (row & 7)) << 3) + (c & 7)] = (_Float16)h;
        }
    }
    // A1 fragments from per-wave h tile (no cross-wave sync needed)
    half8 ah1[2];
    #pragma unroll
    for (int ks = 0; ks < 2; ++ks) {
        int u0 = ks*4 + quad;
        ah1[ks] = *(const half8*)&gt[l16*64 + ((u0 ^ (l16 & 7)) << 3)];
    }
    __syncthreads();                                            // B4
    *(half8*)&WAH[sdst] = *(const half8*)&whh[8192 + srow*64 + su*8];
    *(half8*)&WAL[sdst] = *(const half8*)&wll[8192 + srow*64 + su*8];
    __syncthreads();                                            // B5

    f32x4 acc2[4] = {};
    // ================ half 0: G cols 0..63 ================
    {
        f32x4 a1[4] = {};
        #pragma unroll
        for (int ks = 0; ks < 2; ++ks) {
            int u0 = ks*4 + quad;
            #pragma unroll
            for (int t = 0; t < 4; ++t) {
                int row = t*16 + l16;
                a1[t] = __builtin_amdgcn_mfma_f32_16x16x32_f16(ah1[ks], BFRAG(WAH,row,u0), a1[t], 0,0,0);
                a1[t] = __builtin_amdgcn_mfma_f32_16x16x32_f16(ah1[ks], BFRAG(WAL,row,u0), a1[t], 0,0,0);
            }
        }
        #pragma unroll
        for (int t = 0; t < 4; ++t) {
            float b1v = bb1[t*16 + l16];
            #pragma unroll
            for (int r = 0; r < 4; ++r) {
                int row = quad*4 + r;
                int c = t*16 + l16;
                int u = c >> 3;
                gt[row*64 + ((u ^ (row & 7)) << 3) + (c & 7)] =
                    (_Float16)gelu_exact(a1[t][r] + b1v);
            }
        }
        #pragma unroll
        for (int ks2 = 0; ks2 < 2; ++ks2) {
            int u0 = ks2*4 + quad;
            half8 ag = *(const half8*)&gt[l16*64 + ((u0 ^ (l16 & 7)) << 3)];
            #pragma unroll
            for (int nt2 = 0; nt2 < 4; ++nt2) {
                int row = nt2*16 + l16;
                acc2[nt2] = __builtin_amdgcn_mfma_f32_16x16x32_f16(ag, BFRAG(W2H,row,u0), acc2[nt2], 0,0,0);
                acc2[nt2] = __builtin_amdgcn_mfma_f32_16x16x32_f16(ag, BFRAG(W2L,row,u0), acc2[nt2], 0,0,0);
            }
        }
    }
    __syncthreads();                                            // B6
    *(half8*)&WAH[sdst] = *(const half8*)&whh[8192 + (64 + srow)*64 + su*8];
    *(half8*)&WAL[sdst] = *(const half8*)&wll[8192 + (64 + srow)*64 + su*8];
    *(half8*)&W2H[sdst] = *(const half8*)&whh[16384 + srow*128 + 64 + su*8];
    *(half8*)&W2L[sdst] = *(const half8*)&wll[16384 + srow*128 + 64 + su*8];
    __syncthreads();                                            // B7
    // ================ half 1: G cols 64..127 ================
    {
        f32x4 a1[4] = {};
        #pragma unroll
        for (int ks = 0; ks < 2; ++ks) {
            int u0 = ks*4 + quad;
            #pragma unroll
            for (int t = 0; t < 4; ++t) {
                int row = t*16 + l16;
                a1[t] = __builtin_amdgcn_mfma_f32_16x16x32_f16(ah1[ks], BFRAG(WAH,row,u0), a1[t], 0,0,0);
                a1[t] = __builtin_amdgcn_mfma_f32_16x16x32_f16(ah1[ks], BFRAG(WAL,row,u0), a1[t], 0,0,0);
            }
        }
        #pragma unroll
        for (int t = 0; t < 4; ++t) {
            float b1v = bb1[64 + t*16 + l16];
            #pragma unroll
            for (int r = 0; r < 4; ++r) {
                int row = quad*4 + r;
                int c = t*16 + l16;
                int u = c >> 3;
                gt[row*64 + ((u ^ (row & 7)) << 3) + (c & 7)] =
                    (_Float16)gelu_exact(a1[t][r] + b1v);
            }
        }
        #pragma unroll
        for (int ks2 = 0; ks2 < 2; ++ks2) {
            int u0 = ks2*4 + quad;
            half8 ag = *(const half8*)&gt[l16*64 + ((u0 ^ (l16 & 7)) << 3)];
            #pragma unroll
            for (int nt2 = 0; nt2 < 4; ++nt2) {
                int row = nt2*16 + l16;
                acc2[nt2] = __builtin_amdgcn_mfma_f32_16x16x32_f16(ag, BFRAG(W2H,row,u0), acc2[nt2], 0,0,0);
                acc2[nt2] = __builtin_amdgcn_mfma_f32_16x16x32_f16(ag, BFRAG(W2L,row,u0), acc2[nt2], 0,0,0);
            }
        }
    }

    // ---- epilogue: m = acc2 + hn + b2; out = LN2(m) ----
    #pragma unroll
    for (int r = 0; r < 4; ++r) {
        int n = nb + quad * 4 + r;
        float mv[4];
        #pragma unroll
        for (int nt = 0; nt < 4; ++nt)
            mv[nt] = acc2[nt][r] + hn[r][nt] + bb2[nt*16 + l16];
        float s = mv[0] + mv[1] + mv[2] + mv[3];
        #pragma unroll
        for (int o = 1; o < 16; o <<= 1) s += __shfl_xor(s, o);
        float mu = s * (1.0f/64.0f);
        float q = 0.f;
        #pragma unroll
        for (int nt = 0; nt < 4; ++nt) { float t = mv[nt] - mu; q += t*t; }
        #pragma unroll
        for (int o = 1; o < 16; o <<= 1) q += __shfl_xor(q, o);
        float rs = rsqrtf(q * (1.0f/64.0f) + 1e-5f);
        if (n < NN) {
            #pragma unroll
            for (int nt = 0; nt < 4; ++nt) {
                int c = nt*16 + l16;
                out[(size_t)n * 64 + c] = (mv[nt] - mu) * rs * g2[c] + be2[c];
            }
        }
    }
}

extern "C" void kernel_launch(void* const* d_in, const int* in_sizes, int n_in,
                              void* d_out, int out_size, void* d_ws, size_t ws_size,
                              hipStream_t stream) {
    const float* x    = (const float*)d_in[0];
    const int*   ei   = (const int*)d_in[1];
    const float* rf   = (const float*)d_in[2];
    const float* Wp   = (const float*)d_in[3];
    const float* Wn   = (const float*)d_in[4];
    const float* attw = (const float*)d_in[5];
    const float* cf   = (const float*)d_in[6];
    const float* w1   = (const float*)d_in[7];
    const float* b1   = (const float*)d_in[8];
    const float* w2   = (const float*)d_in[9];
    const float* b2   = (const float*)d_in[10];
    const float* g1   = (const float*)d_in[11];
    const float* be1  = (const float*)d_in[12];
    const float* g2   = (const float*)d_in[13];
    const float* be2  = (const float*)d_in[14];
    float* out = (float*)d_out;

    float* ws = (float*)d_ws;
    float*     es1 = ws;                                   // NN f32
    _Float16*  uvh = (_Float16*)(es1 + NN);                // NN*128 fp16
    _Float16*  whh = uvh + (size_t)NN * 128;               // 24576 fp16
    _Float16*  wll = whh + 24576;                          // 24576 fp16
    uint2*  sorted = (uint2*)(wll + 24576);                // NE uint2
    int*    off    = (int*)(sorted + NE);                  // NN+1
    int*    bcount = off + NN + 1;                         // NBUK
    int*    bbase  = bcount + NBUK;                        // NBUK+1
    uintptr_t xp = ((uintptr_t)(bbase + NBUK + 1) + 15) & ~(uintptr_t)15;
    _Float16* xh = (_Float16*)xp;                          // NN*64 fp16
    uint2*  tmp    = (uint2*)uvh;                          // padded NBUK*BSTRIDE uint2 (19.2MB < 25.6MB)

    hipMemsetAsync(bcount, 0, NBUK * sizeof(int), stream);

    kfront    <<<NTB + NWB + NPB, 256, 0, stream>>>(ei, rf, bcount, tmp,
                 Wp, Wn, w1, w2, cf, whh, wll, x, attw, es1, xh);
    ks_bscan  <<<1, 1024, 0, stream>>>(bcount, bbase);
    kscat2    <<<NBUK, 256, 0, stream>>>(tmp, bcount, bbase, es1, off, sorted);
    k4a_agg   <<<NN/4, 256, 0, stream>>>(sorted, off, xh, uvh);
    k4b5      <<<(NN+127)/128, 512, 0, stream>>>(uvh, whh, wll, x, g1, be1, b1, b2, g2, be2, out);
}